// Round 8
// baseline (4985.923 us; speedup 1.0000x reference)
//
#include <hip/hip_runtime.h>
#include <hip/hip_cooperative_groups.h>

namespace cg = cooperative_groups;

// CAGenerator: 64-step neural CA — ONE cooperative dispatch for all steps.
// R22: R16's kS body verbatim (best measured), but the 64 dependent
//   dispatches are replaced by a persistent cooperative kernel with
//   grid.sync() between steps. Tests the last standing hypothesis:
//   per-dispatch serial cost (drain -> CP barrier + cross-XCD L2
//   writeback/invalidate -> ramp -> cold caches) is the invariant ~8-10us
//   that survived every in-kernel restructure (R17/R18/R19/R20/R21 all
//   within +-10% of R16 despite 2-7x changes in bytes/work/iters).
//   Also the diagnostic: a ~1ms single dispatch is top-1 in rocprof ->
//   first real MfmaUtil/VALUBusy/FETCH counters for this workload.
//   Hoisted out of the step loop: bcL/b3L, pxh, msT halo-zero.
//   U/A ping-pong by step parity; final dout epilogue folded in.
// Folded: Wc = W2@W1 (512x720), bc = W2@b1+b2. mask=uniform()<1.0 -> no RNG.

#define NPIX 8192
#define T_ALIVE 0.01f

typedef _Float16 f16;
typedef __attribute__((ext_vector_type(8)))  _Float16 h8_t;
typedef __attribute__((ext_vector_type(4)))  _Float16 h4_t;
typedef __attribute__((ext_vector_type(16))) float    fx16;

// ---------------------------------------------------------------------------
// Prep (unchanged)
// ---------------------------------------------------------------------------
__global__ __launch_bounds__(256) void tr512(
    const float* __restrict__ W2, float* __restrict__ W2T)
{
    __shared__ float t[32][33];
    const int bx = blockIdx.x & 15, by = blockIdx.x >> 4;
    const int x = threadIdx.x & 31, y8 = threadIdx.x >> 5;
#pragma unroll
    for (int r = 0; r < 32; r += 8)
        t[r + y8][x] = W2[(size_t)(by * 32 + r + y8) * 512 + bx * 32 + x];
    __syncthreads();
#pragma unroll
    for (int r = 0; r < 32; r += 8)
        W2T[(size_t)(bx * 32 + r + y8) * 512 + by * 32 + x] = t[x][r + y8];
}

__global__ __launch_bounds__(256) void wc32(
    const float* __restrict__ W2T, const float* __restrict__ W1,
    float* __restrict__ Wc)
{
    __shared__ float As[16][32];
    __shared__ float Bs[16][32];
    const int tid = threadIdx.x;
    const int ty = tid >> 3, tx = tid & 7;
    const int m0 = blockIdx.y * 32, n0 = blockIdx.x * 32;
    float acc[4] = {0.f, 0.f, 0.f, 0.f};

    for (int k0 = 0; k0 < 512; k0 += 16) {
#pragma unroll
        for (int t = 0; t < 2; ++t) {
            const int idx = tid + t * 256;
            const int r = idx >> 5, c = idx & 31;
            As[r][c] = W2T[(size_t)(k0 + r) * 512 + m0 + c];
            const int n = n0 + c;
            Bs[r][c] = (n < 720) ? W1[(size_t)(k0 + r) * 720 + n] : 0.f;
        }
        __syncthreads();
#pragma unroll
        for (int kk = 0; kk < 16; ++kk) {
            const float a = As[kk][ty];
#pragma unroll
            for (int j = 0; j < 4; ++j)
                acc[j] = fmaf(a, Bs[kk][tx * 4 + j], acc[j]);
        }
        __syncthreads();
    }
    const int m = m0 + ty;
#pragma unroll
    for (int j = 0; j < 4; ++j) {
        const int n = n0 + tx * 4 + j;
        if (n < 720) Wc[(size_t)m * 720 + n] = acc[j];
    }
}

__global__ __launch_bounds__(256) void bc_k(
    const float* __restrict__ W2, const float* __restrict__ b1,
    const float* __restrict__ b2, float* __restrict__ bc)
{
    const int m = blockIdx.x * 256 + threadIdx.x;
    if (m >= 512) return;
    float a = b2[m];
    for (int h = 0; h < 512; ++h) a += W2[m * 512 + h] * b1[h];
    bc[m] = a;
}

// 32x32x16 A-frags, K permuted (kp = tap*80+ci), 720 = 45*16 exactly.
__global__ __launch_bounds__(256) void swz_wc2(
    const float* __restrict__ Wc, f16* __restrict__ Wcsw2)
{
    const int idx = blockIdx.x * 256 + threadIdx.x;
    if (idx >= 45 * 16 * 64) return;
    const int lane = idx & 63;
    const int t = idx >> 6;
    const int mtg = t & 15, ks = t >> 4;
    const int m = mtg * 32 + (lane & 31);
    const int k0 = ks * 16 + (lane >> 5) * 8;
    h8_t v;
#pragma unroll
    for (int j = 0; j < 8; ++j) {
        const int kp = k0 + j;
        const int tap = kp / 80, ci = kp - tap * 80;
        v[j] = (f16)Wc[(size_t)m * 720 + ci * 9 + tap];
    }
    *(h8_t*)(Wcsw2 + (size_t)idx * 8) = v;
}

// 32x32x16 A-frags for W3 (80x512 padded to 96 rows).
__global__ __launch_bounds__(256) void swz_w32(
    const float* __restrict__ W3, f16* __restrict__ W3sw2)
{
    const int idx = blockIdx.x * 256 + threadIdx.x;
    if (idx >= 32 * 3 * 64) return;
    const int lane = idx & 63;
    const int t = idx >> 6;
    const int mt = t % 3, ks2 = t / 3;
    const int m = mt * 32 + (lane & 31);
    const int k0 = ks2 * 16 + (lane >> 5) * 8;
    h8_t v;
#pragma unroll
    for (int j = 0; j < 8; ++j)
        v[j] = (f16)((m < 80) ? W3[(size_t)m * 512 + k0 + j] : 0.f);
    *(h8_t*)(W3sw2 + (size_t)idx * 8) = v;
}

// Seed: U_{-1} := S_0 (fp32 ch-major), A_{-1} := S_0 ch0.
__global__ __launch_bounds__(256) void seed2(
    const float* __restrict__ z, float* __restrict__ U0,
    float* __restrict__ A0)
{
    const int idx = blockIdx.x * 256 + threadIdx.x;
    if (idx >= 640) return;
    const int b = idx / 80, c = idx - b * 80;
    const int n = b * 1024 + 16 * 32 + 16;
    const float v = (c == 0) ? 1.f : z[b * 100 + (c - 1)];
    U0[(size_t)c * NPIX + n] = v;
    if (c == 0) A0[n] = 1.f;
}

// ---------------------------------------------------------------------------
// kAll: all 64 steps, persistent. grid 256 x 512 thr: b=blk>>5, y=blk&31.
//   Step body == R16 kS. grid.sync() between steps (cross-XCD coherence via
//   CG's agent-scope release/acquire). Final dout epilogue at the end.
// ---------------------------------------------------------------------------
__global__ __launch_bounds__(512) void kAll(
    const f16* __restrict__ Wcsw2, const float* __restrict__ bc,
    const f16* __restrict__ W3sw2, const float* __restrict__ b3,
    float* __restrict__ U0, float* __restrict__ U1,
    float* __restrict__ A0, float* __restrict__ A1,
    float* __restrict__ dout)
{
    cg::grid_group grid = cg::this_grid();

    __shared__ f16   msT[8160];     // 10 cc x (3 rows x 34 px) x 8 halfs
    __shared__ f16   Hsw[16384];    // 64 co x 32 px x 8 halfs = 32 KB
    __shared__ float bcL[512];
    __shared__ float b3L[80];
    __shared__ float SrowL[2560];   // S_s own row, fp32
    __shared__ float N5[160];       // U ch0 rows y-2..y+2
    __shared__ float A5[160];       // alpha  rows y-2..y+2
    __shared__ float live3[96];     // live rows y-1..y+1

    const int tid = threadIdx.x;
    const int lane = tid & 63, w = tid >> 6;     // w = 0..7
    const int li = lane & 31, q2 = lane >> 5;
    const int blk = blockIdx.x;
    const int b = blk >> 5, y = blk & 31;
    const int gb = b * 1024;

    // hoisted invariants
    if (tid < 512) bcL[tid] = bc[tid];
    if (tid < 80)  b3L[tid] = b3[tid];
    {   // zero msT once (halo cols 0/33 + OOB rows stay zero forever;
        // interior cols 1..32 are fully rewritten every step)
        h8_t zz;
#pragma unroll
        for (int j = 0; j < 8; ++j) zz[j] = (f16)0.f;
        for (int i = tid; i < 1020; i += 512)
            *(h8_t*)(msT + (size_t)i * 8) = zz;
    }
    int pxh[9];
#pragma unroll
    for (int t = 0; t < 9; ++t)
        pxh[t] = ((t / 3) * 34 + li + (t % 3)) * 8;

#pragma clang loop unroll(disable)
    for (int s = 0; s < 64; ++s) {
        const float* Uin  = (s & 1) ? U1 : U0;
        float*       Uout = (s & 1) ? U0 : U1;
        const float* Ain  = (s & 1) ? A1 : A0;
        float*       Aout = (s & 1) ? A0 : A1;

        // weight-ring prefetch (in flight during the build phase)
        h8_t abuf[8][2];
#pragma unroll
        for (int pk = 0; pk < 8; ++pk)
#pragma unroll
            for (int i = 0; i < 2; ++i)
                abuf[pk][i] = *(const h8_t*)(Wcsw2 +
                    (((size_t)pk * 16 + (w * 2 + i)) * 64 + lane) * 8);

        // ---------------- build phase ------------------------------------
        if (tid < 160) {
            const int r = tid >> 5, x = tid & 31, yy = y - 2 + r;
            const bool ok = ((unsigned)yy < 32u);
            N5[tid] = ok ? Uin[gb + yy * 32 + x] : -1e30f;
            A5[tid] = ok ? Ain[gb + yy * 32 + x] : -1e30f;
        }
        __syncthreads();

        if (tid < 96) {   // live(r,x) rows y-1..y+1
            const int r = tid >> 5, x = tid & 31;
            float mN = -1e30f, mA = -1e30f;
#pragma unroll
            for (int rr = 0; rr < 3; ++rr)
#pragma unroll
                for (int dx = -1; dx <= 1; ++dx) {
                    const int xx = x + dx;
                    if ((unsigned)xx < 32u) {
                        mN = fmaxf(mN, N5[(r + rr) * 32 + xx]);
                        mA = fmaxf(mA, A5[(r + rr) * 32 + xx]);
                    }
                }
            live3[tid] = (mN > T_ALIVE && mA > T_ALIVE) ? 1.f : 0.f;
        }
        __syncthreads();

        // S_s = Uin * live: 3 rows x 80 ch x 32 px = 7680 elems
#pragma unroll
        for (int it = 0; it < 15; ++it) {
            const int e = tid + it * 512;
            const int x = e & 31;
            const int t2 = e >> 5;
            const int r = t2 / 80, ch = t2 - r * 80;
            const int yy = y - 1 + r;
            float v = 0.f;
            if ((unsigned)yy < 32u)
                v = Uin[(size_t)ch * NPIX + gb + yy * 32 + x] * live3[r * 32 + x];
            msT[(size_t)((ch >> 3) * 102 + r * 34 + x + 1) * 8 + (ch & 7)] = (f16)v;
            if (r == 1) {
                SrowL[ch * 32 + x] = v;
                if (ch == 0) Aout[gb + y * 32 + x] = v;
            }
        }
        __syncthreads();

        // ---------------- phase 1: H chunk (64 ch x 32 px) per wave -------
        fx16 acc[2];
#pragma unroll
        for (int i = 0; i < 2; ++i)
#pragma unroll
            for (int r = 0; r < 16; ++r) acc[i][r] = 0.f;

#pragma unroll
        for (int ks = 0; ks < 45; ++ks) {
            const int o0 = 2 * ks, o1 = 2 * ks + 1;
            const int a0 = (o0 % 10) * 816 + pxh[o0 / 10];
            const int a1 = (o1 % 10) * 816 + pxh[o1 / 10];
            const h8_t bf = *(const h8_t*)(msT + (q2 ? a1 : a0));
            h8_t av[2];
#pragma unroll
            for (int i = 0; i < 2; ++i) av[i] = abuf[ks & 7][i];
            if (ks + 8 < 45) {
#pragma unroll
                for (int i = 0; i < 2; ++i)
                    abuf[ks & 7][i] = *(const h8_t*)(Wcsw2 +
                        (((size_t)(ks + 8) * 16 + (w * 2 + i)) * 64 + lane) * 8);
            }
#pragma unroll
            for (int i = 0; i < 2; ++i)
                acc[i] = __builtin_amdgcn_mfma_f32_32x32x16_f16(
                    av[i], bf, acc[i], 0, 0, 0);
        }

        // relu(acc + bc) -> Hsw octets (octet co holds channels 8co..8co+7)
#pragma unroll
        for (int i = 0; i < 2; ++i) {
#pragma unroll
            for (int aa = 0; aa < 4; ++aa) {
                const int chl = i * 32 + 8 * aa + 4 * q2;
                const int co = w * 8 + i * 4 + aa;
                h4_t v4;
#pragma unroll
                for (int rb = 0; rb < 4; ++rb)
                    v4[rb] = (f16)fmaxf(acc[i][aa * 4 + rb] + bcL[w * 64 + chl + rb], 0.f);
                *(h4_t*)(Hsw + ((size_t)co * 32 + li) * 8 + 4 * q2) = v4;
            }
        }
        __syncthreads();

        // ---------------- phase 2: upd = W3*H full-K (waves 0..2) ---------
        if (w < 3) {
            const int mt = w;
            h8_t ar[8];
#pragma unroll
            for (int pk = 0; pk < 8; ++pk)
                ar[pk] = *(const h8_t*)(W3sw2 +
                    (((size_t)pk * 3 + mt) * 64 + lane) * 8);

            fx16 acc3;
#pragma unroll
            for (int r = 0; r < 16; ++r) acc3[r] = 0.f;
#pragma unroll
            for (int ks2 = 0; ks2 < 32; ++ks2) {
                const h8_t bf = *(const h8_t*)(Hsw +
                    ((size_t)(ks2 * 2 + q2) * 32 + li) * 8);
                const h8_t a = ar[ks2 & 7];
                if (ks2 + 8 < 32)
                    ar[ks2 & 7] = *(const h8_t*)(W3sw2 +
                        (((size_t)(ks2 + 8) * 3 + mt) * 64 + lane) * 8);
                acc3 = __builtin_amdgcn_mfma_f32_32x32x16_f16(a, bf, acc3, 0, 0, 0);
            }

            // U = S_s + upd + b3 (unmasked); next step's build applies mask
            const size_t px = (size_t)(gb + y * 32 + li);
#pragma unroll
            for (int aa = 0; aa < 4; ++aa)
#pragma unroll
                for (int rb = 0; rb < 4; ++rb) {
                    const int ch = mt * 32 + rb + 8 * aa + 4 * q2;
                    if (ch < 80) {
                        Uout[(size_t)ch * NPIX + px] =
                            SrowL[ch * 32 + li] + acc3[aa * 4 + rb] + b3L[ch];
                    }
                }
        }

        grid.sync();
    }

    // ---------------- final: dout = U63 ch0 * live63 (U63 in U0/A0) -------
    if (tid < 96) {
        const int r = tid >> 5, x = tid & 31, yy = y - 1 + r;
        const bool ok = ((unsigned)yy < 32u);
        N5[tid] = ok ? U0[gb + yy * 32 + x] : -1e30f;
        A5[tid] = ok ? A0[gb + yy * 32 + x] : -1e30f;
    }
    __syncthreads();

    if (tid < 32) {
        float mN = -1e30f, mA = -1e30f;
#pragma unroll
        for (int rr = 0; rr < 3; ++rr)
#pragma unroll
            for (int dx = -1; dx <= 1; ++dx) {
                const int xx = tid + dx;
                if ((unsigned)xx < 32u) {
                    mN = fmaxf(mN, N5[rr * 32 + xx]);
                    mA = fmaxf(mA, A5[rr * 32 + xx]);
                }
            }
        const float lv = (mN > T_ALIVE && mA > T_ALIVE) ? 1.f : 0.f;
        dout[gb + y * 32 + tid] = U0[gb + y * 32 + tid] * lv;
    }
}

// ---------------------------------------------------------------------------
extern "C" void kernel_launch(void* const* d_in, const int* in_sizes, int n_in,
                              void* d_out, int out_size, void* d_ws, size_t ws_size,
                              hipStream_t stream)
{
    const float* z  = (const float*)d_in[0];
    const float* W1 = (const float*)d_in[1];   // 512 x 720
    const float* b1 = (const float*)d_in[2];
    const float* W2 = (const float*)d_in[3];   // 512 x 512
    const float* b2 = (const float*)d_in[4];
    const float* W3 = (const float*)d_in[5];   // 80 x 512
    const float* b3 = (const float*)d_in[6];

    char* ws = (char*)d_ws;
    float* U0    = (float*)ws;  ws += (size_t)80 * NPIX * 4;
    float* U1    = (float*)ws;  ws += (size_t)80 * NPIX * 4;
    float* A0    = (float*)ws;  ws += (size_t)NPIX * 4;
    float* A1    = (float*)ws;  ws += (size_t)NPIX * 4;
    float* bc    = (float*)ws;  ws += 512 * 4;
    float* Wc    = (float*)ws;  ws += (size_t)512 * 720 * 4;
    float* W2T   = (float*)ws;  ws += (size_t)512 * 512 * 4;
    f16*   Wcsw2 = (f16*)ws;   ws += (size_t)45 * 16 * 64 * 8 * 2;
    f16*   W3sw2 = (f16*)ws;   ws += (size_t)32 * 3 * 64 * 8 * 2;

    hipMemsetAsync(U0, 0, (size_t)80 * NPIX * 4, stream);
    hipMemsetAsync(A0, 0, (size_t)NPIX * 4, stream);
    seed2<<<3, 256, 0, stream>>>(z, U0, A0);
    tr512<<<256, 256, 0, stream>>>(W2, W2T);
    wc32<<<dim3(23, 16), 256, 0, stream>>>(W2T, W1, Wc);
    bc_k<<<2, 256, 0, stream>>>(W2, b1, b2, bc);
    swz_wc2<<<180, 256, 0, stream>>>(Wc, Wcsw2);
    swz_w32<<<24, 256, 0, stream>>>(W3, W3sw2);

    const f16*   Wcsw2c = Wcsw2;
    const float* bcc    = bc;
    const f16*   W3c    = W3sw2;
    const float* b3c    = b3;
    float*       doutp  = (float*)d_out;
    void* args[] = {
        (void*)&Wcsw2c, (void*)&bcc, (void*)&W3c, (void*)&b3c,
        (void*)&U0, (void*)&U1, (void*)&A0, (void*)&A1, (void*)&doutp
    };
    hipLaunchCooperativeKernel((void*)kAll, dim3(256), dim3(512),
                               args, 0, stream);
}

// Round 9
// 2322.615 us; speedup vs baseline: 2.1467x; 2.1467x over previous
//
#include <hip/hip_runtime.h>

// CAGenerator: 64-step neural CA — ONE dispatch/step (R16 path, unchanged)
// R23: R16 + two measurement probes appended AFTER the real output:
//   kW<64>: one dispatch, 64 internal reps of kS's exact phase-1 weight
//     stream (ring-8, 45 iters, 2 MFMA/iter). No barriers/state. Lands
//     top-1 in rocprof -> isolated stream counters (dur, FETCH, MfmaUtil).
//   kW<1> x64: same body, one rep per dispatch -> stream time including
//     kernel-boundary cache invalidate/refill. (T_wb - T_mono/64) = the
//     per-dispatch L2-refill tax, measured directly.
//   Rationale: R22's coop counters (FETCH 76MB/step after grid.sync L2
//   flush) resurrect the per-XCD-refill model, which fits the entire
//   R16-R21 invariance ledger. This round buys the decisive number before
//   committing to multi-step fusion.
// Probes read Wcsw2 (read-only) and write nothing (guard never taken);
// output path is bit-identical to R16.

#define NPIX 8192
#define T_ALIVE 0.01f

typedef _Float16 f16;
typedef __attribute__((ext_vector_type(8)))  _Float16 h8_t;
typedef __attribute__((ext_vector_type(4)))  _Float16 h4_t;
typedef __attribute__((ext_vector_type(16))) float    fx16;

// ---------------------------------------------------------------------------
// Prep (unchanged)
// ---------------------------------------------------------------------------
__global__ __launch_bounds__(256) void tr512(
    const float* __restrict__ W2, float* __restrict__ W2T)
{
    __shared__ float t[32][33];
    const int bx = blockIdx.x & 15, by = blockIdx.x >> 4;
    const int x = threadIdx.x & 31, y8 = threadIdx.x >> 5;
#pragma unroll
    for (int r = 0; r < 32; r += 8)
        t[r + y8][x] = W2[(size_t)(by * 32 + r + y8) * 512 + bx * 32 + x];
    __syncthreads();
#pragma unroll
    for (int r = 0; r < 32; r += 8)
        W2T[(size_t)(bx * 32 + r + y8) * 512 + by * 32 + x] = t[x][r + y8];
}

__global__ __launch_bounds__(256) void wc32(
    const float* __restrict__ W2T, const float* __restrict__ W1,
    float* __restrict__ Wc)
{
    __shared__ float As[16][32];
    __shared__ float Bs[16][32];
    const int tid = threadIdx.x;
    const int ty = tid >> 3, tx = tid & 7;
    const int m0 = blockIdx.y * 32, n0 = blockIdx.x * 32;
    float acc[4] = {0.f, 0.f, 0.f, 0.f};

    for (int k0 = 0; k0 < 512; k0 += 16) {
#pragma unroll
        for (int t = 0; t < 2; ++t) {
            const int idx = tid + t * 256;
            const int r = idx >> 5, c = idx & 31;
            As[r][c] = W2T[(size_t)(k0 + r) * 512 + m0 + c];
            const int n = n0 + c;
            Bs[r][c] = (n < 720) ? W1[(size_t)(k0 + r) * 720 + n] : 0.f;
        }
        __syncthreads();
#pragma unroll
        for (int kk = 0; kk < 16; ++kk) {
            const float a = As[kk][ty];
#pragma unroll
            for (int j = 0; j < 4; ++j)
                acc[j] = fmaf(a, Bs[kk][tx * 4 + j], acc[j]);
        }
        __syncthreads();
    }
    const int m = m0 + ty;
#pragma unroll
    for (int j = 0; j < 4; ++j) {
        const int n = n0 + tx * 4 + j;
        if (n < 720) Wc[(size_t)m * 720 + n] = acc[j];
    }
}

__global__ __launch_bounds__(256) void bc_k(
    const float* __restrict__ W2, const float* __restrict__ b1,
    const float* __restrict__ b2, float* __restrict__ bc)
{
    const int m = blockIdx.x * 256 + threadIdx.x;
    if (m >= 512) return;
    float a = b2[m];
    for (int h = 0; h < 512; ++h) a += W2[m * 512 + h] * b1[h];
    bc[m] = a;
}

// 32x32x16 A-frags, K permuted (kp = tap*80+ci), 720 = 45*16 exactly.
__global__ __launch_bounds__(256) void swz_wc2(
    const float* __restrict__ Wc, f16* __restrict__ Wcsw2)
{
    const int idx = blockIdx.x * 256 + threadIdx.x;
    if (idx >= 45 * 16 * 64) return;
    const int lane = idx & 63;
    const int t = idx >> 6;
    const int mtg = t & 15, ks = t >> 4;
    const int m = mtg * 32 + (lane & 31);
    const int k0 = ks * 16 + (lane >> 5) * 8;
    h8_t v;
#pragma unroll
    for (int j = 0; j < 8; ++j) {
        const int kp = k0 + j;
        const int tap = kp / 80, ci = kp - tap * 80;
        v[j] = (f16)Wc[(size_t)m * 720 + ci * 9 + tap];
    }
    *(h8_t*)(Wcsw2 + (size_t)idx * 8) = v;
}

// 32x32x16 A-frags for W3 (80x512 padded to 96 rows).
__global__ __launch_bounds__(256) void swz_w32(
    const float* __restrict__ W3, f16* __restrict__ W3sw2)
{
    const int idx = blockIdx.x * 256 + threadIdx.x;
    if (idx >= 32 * 3 * 64) return;
    const int lane = idx & 63;
    const int t = idx >> 6;
    const int mt = t % 3, ks2 = t / 3;
    const int m = mt * 32 + (lane & 31);
    const int k0 = ks2 * 16 + (lane >> 5) * 8;
    h8_t v;
#pragma unroll
    for (int j = 0; j < 8; ++j)
        v[j] = (f16)((m < 80) ? W3[(size_t)m * 512 + k0 + j] : 0.f);
    *(h8_t*)(W3sw2 + (size_t)idx * 8) = v;
}

// Seed: U_{-1} := S_0 (fp32 ch-major), A_{-1} := S_0 ch0.
__global__ __launch_bounds__(256) void seed2(
    const float* __restrict__ z, float* __restrict__ U0,
    float* __restrict__ A0)
{
    const int idx = blockIdx.x * 256 + threadIdx.x;
    if (idx >= 640) return;
    const int b = idx / 80, c = idx - b * 80;
    const int n = b * 1024 + 16 * 32 + 16;
    const float v = (c == 0) ? 1.f : z[b * 100 + (c - 1)];
    U0[(size_t)c * NPIX + n] = v;
    if (c == 0) A0[n] = 1.f;
}

// ---------------------------------------------------------------------------
// kS: one full CA step (R16, unchanged). grid 256 x 512: b=blk>>5, y=blk&31.
// ---------------------------------------------------------------------------
__global__ __launch_bounds__(512) void kS(
    const f16* __restrict__ Wcsw2, const float* __restrict__ bc,
    const f16* __restrict__ W3sw2, const float* __restrict__ b3,
    const float* __restrict__ Uin, const float* __restrict__ Ain,
    float* __restrict__ Uout, float* __restrict__ Aout)
{
    __shared__ f16   msT[8160];     // 10 cc x (3 rows x 34 px) x 8 halfs
    __shared__ f16   Hsw[16384];    // 64 co x 32 px x 8 halfs = 32 KB
    __shared__ float bcL[512];
    __shared__ float b3L[80];
    __shared__ float SrowL[2560];   // S_s own row, fp32
    __shared__ float N5[160];       // U ch0 rows y-2..y+2
    __shared__ float A5[160];       // alpha  rows y-2..y+2
    __shared__ float live3[96];     // live rows y-1..y+1

    const int tid = threadIdx.x;
    const int lane = tid & 63, w = tid >> 6;     // w = 0..7
    const int li = lane & 31, q2 = lane >> 5;
    const int blk = blockIdx.x;
    const int b = blk >> 5, y = blk & 31;
    const int gb = b * 1024;

    // early weight-ring prefetch: overlaps the build
    h8_t abuf[8][2];
#pragma unroll
    for (int pk = 0; pk < 8; ++pk)
#pragma unroll
        for (int i = 0; i < 2; ++i)
            abuf[pk][i] = *(const h8_t*)(Wcsw2 +
                (((size_t)pk * 16 + (w * 2 + i)) * 64 + lane) * 8);

    bcL[tid] = bc[tid];
    if (tid < 80) b3L[tid] = b3[tid];

    // ---------------- build phase ----------------------------------------
    if (tid < 160) {
        const int r = tid >> 5, x = tid & 31, yy = y - 2 + r;
        const bool ok = ((unsigned)yy < 32u);
        N5[tid] = ok ? Uin[gb + yy * 32 + x] : -1e30f;
        A5[tid] = ok ? Ain[gb + yy * 32 + x] : -1e30f;
    }
    {   // zero msT (covers halo cols xi=0/33 and out-of-image rows)
        h8_t zz;
#pragma unroll
        for (int j = 0; j < 8; ++j) zz[j] = (f16)0.f;
        for (int i = tid; i < 1020; i += 512)
            *(h8_t*)(msT + (size_t)i * 8) = zz;
    }
    __syncthreads();

    if (tid < 96) {   // live(r,x) for rows y-1..y+1
        const int r = tid >> 5, x = tid & 31;
        float mN = -1e30f, mA = -1e30f;
#pragma unroll
        for (int rr = 0; rr < 3; ++rr)
#pragma unroll
            for (int dx = -1; dx <= 1; ++dx) {
                const int xx = x + dx;
                if ((unsigned)xx < 32u) {
                    mN = fmaxf(mN, N5[(r + rr) * 32 + xx]);
                    mA = fmaxf(mA, A5[(r + rr) * 32 + xx]);
                }
            }
        live3[tid] = (mN > T_ALIVE && mA > T_ALIVE) ? 1.f : 0.f;
    }
    __syncthreads();

    // S_s = Uin * live: 3 rows x 80 ch x 32 px
#pragma unroll
    for (int it = 0; it < 15; ++it) {
        const int e = tid + it * 512;
        const int x = e & 31;
        const int t2 = e >> 5;
        const int r = t2 / 80, ch = t2 - r * 80;
        const int yy = y - 1 + r;
        float v = 0.f;
        if ((unsigned)yy < 32u)
            v = Uin[(size_t)ch * NPIX + gb + yy * 32 + x] * live3[r * 32 + x];
        msT[(size_t)((ch >> 3) * 102 + r * 34 + x + 1) * 8 + (ch & 7)] = (f16)v;
        if (r == 1) {
            SrowL[ch * 32 + x] = v;
            if (ch == 0) Aout[gb + y * 32 + x] = v;
        }
    }
    __syncthreads();

    // ---------------- phase 1: H chunk (64 ch x 32 px) per wave -----------
    int pxh[9];
#pragma unroll
    for (int t = 0; t < 9; ++t)
        pxh[t] = ((t / 3) * 34 + li + (t % 3)) * 8;

    fx16 acc[2];
#pragma unroll
    for (int i = 0; i < 2; ++i)
#pragma unroll
        for (int r = 0; r < 16; ++r) acc[i][r] = 0.f;

#pragma unroll
    for (int ks = 0; ks < 45; ++ks) {
        const int o0 = 2 * ks, o1 = 2 * ks + 1;
        const int a0 = (o0 % 10) * 816 + pxh[o0 / 10];
        const int a1 = (o1 % 10) * 816 + pxh[o1 / 10];
        const h8_t bf = *(const h8_t*)(msT + (q2 ? a1 : a0));
        h8_t av[2];
#pragma unroll
        for (int i = 0; i < 2; ++i) av[i] = abuf[ks & 7][i];
        if (ks + 8 < 45) {
#pragma unroll
            for (int i = 0; i < 2; ++i)
                abuf[ks & 7][i] = *(const h8_t*)(Wcsw2 +
                    (((size_t)(ks + 8) * 16 + (w * 2 + i)) * 64 + lane) * 8);
        }
#pragma unroll
        for (int i = 0; i < 2; ++i)
            acc[i] = __builtin_amdgcn_mfma_f32_32x32x16_f16(
                av[i], bf, acc[i], 0, 0, 0);
    }

    // relu(acc + bc) -> Hsw octet layout
#pragma unroll
    for (int i = 0; i < 2; ++i) {
#pragma unroll
        for (int aa = 0; aa < 4; ++aa) {
            const int chl = i * 32 + 8 * aa + 4 * q2;
            const int co = w * 8 + i * 4 + aa;
            h4_t v4;
#pragma unroll
            for (int rb = 0; rb < 4; ++rb)
                v4[rb] = (f16)fmaxf(acc[i][aa * 4 + rb] + bcL[w * 64 + chl + rb], 0.f);
            *(h4_t*)(Hsw + ((size_t)co * 32 + li) * 8 + 4 * q2) = v4;
        }
    }
    __syncthreads();

    // ---------------- phase 2: upd = W3*H full-K (waves 0..2) -------------
    if (w < 3) {
        const int mt = w;
        h8_t ar[8];
#pragma unroll
        for (int pk = 0; pk < 8; ++pk)
            ar[pk] = *(const h8_t*)(W3sw2 +
                (((size_t)pk * 3 + mt) * 64 + lane) * 8);

        fx16 acc3;
#pragma unroll
        for (int r = 0; r < 16; ++r) acc3[r] = 0.f;
#pragma unroll
        for (int ks2 = 0; ks2 < 32; ++ks2) {
            const h8_t bf = *(const h8_t*)(Hsw +
                ((size_t)(ks2 * 2 + q2) * 32 + li) * 8);
            const h8_t a = ar[ks2 & 7];
            if (ks2 + 8 < 32)
                ar[ks2 & 7] = *(const h8_t*)(W3sw2 +
                    (((size_t)(ks2 + 8) * 3 + mt) * 64 + lane) * 8);
            acc3 = __builtin_amdgcn_mfma_f32_32x32x16_f16(a, bf, acc3, 0, 0, 0);
        }

        // U = S_s + upd + b3 (unmasked)
        const size_t px = (size_t)(gb + y * 32 + li);
#pragma unroll
        for (int aa = 0; aa < 4; ++aa)
#pragma unroll
            for (int rb = 0; rb < 4; ++rb) {
                const int ch = mt * 32 + rb + 8 * aa + 4 * q2;
                if (ch < 80) {
                    Uout[(size_t)ch * NPIX + px] =
                        SrowL[ch * 32 + li] + acc3[aa * 4 + rb] + b3L[ch];
                }
            }
    }
}

// ---------------------------------------------------------------------------
// kF: dout = U63 ch0 * live63. grid 256 x 128 thr.
// ---------------------------------------------------------------------------
__global__ __launch_bounds__(128) void kF(
    const float* __restrict__ Uf, const float* __restrict__ Af,
    float* __restrict__ dout)
{
    __shared__ float N3[96];
    __shared__ float A3[96];
    const int tid = threadIdx.x;
    const int blk = blockIdx.x;
    const int b = blk >> 5, y = blk & 31;
    const int gb = b * 1024;

    if (tid < 96) {
        const int r = tid >> 5, x = tid & 31, yy = y - 1 + r;
        const bool ok = ((unsigned)yy < 32u);
        N3[tid] = ok ? Uf[gb + yy * 32 + x] : -1e30f;
        A3[tid] = ok ? Af[gb + yy * 32 + x] : -1e30f;
    }
    __syncthreads();

    if (tid < 32) {
        float mN = -1e30f, mA = -1e30f;
#pragma unroll
        for (int rr = 0; rr < 3; ++rr)
#pragma unroll
            for (int dx = -1; dx <= 1; ++dx) {
                const int xx = tid + dx;
                if ((unsigned)xx < 32u) {
                    mN = fmaxf(mN, N3[rr * 32 + xx]);
                    mA = fmaxf(mA, A3[rr * 32 + xx]);
                }
            }
        const float lv = (mN > T_ALIVE && mA > T_ALIVE) ? 1.f : 0.f;
        dout[gb + y * 32 + tid] = Uf[gb + y * 32 + tid] * lv;
    }
}

// ---------------------------------------------------------------------------
// kW<REP>: weight-stream probe. Exact kS phase-1 ring loop, REP reps,
//   no barriers/state. Guard-write keeps everything live; never executes.
// ---------------------------------------------------------------------------
template<int REP>
__global__ __launch_bounds__(512) void kW(
    const f16* __restrict__ Wcsw2, float* __restrict__ sink)
{
    __shared__ f16 msT[8160];
    __shared__ f16 pad[24000];   // bring LDS to ~63 KB (match kS occupancy)

    const int tid = threadIdx.x;
    const int lane = tid & 63, w = tid >> 6;
    const int li = lane & 31, q2 = lane >> 5;

    {   // zero msT (avoid NaN MFMA inputs); touch pad to keep it allocated
        h8_t zz;
#pragma unroll
        for (int j = 0; j < 8; ++j) zz[j] = (f16)0.f;
        for (int i = tid; i < 1020; i += 512)
            *(h8_t*)(msT + (size_t)i * 8) = zz;
        if (tid < 64) *(h8_t*)(pad + (size_t)tid * 8) = zz;
    }
    __syncthreads();

    int pxh[9];
#pragma unroll
    for (int t = 0; t < 9; ++t)
        pxh[t] = ((t / 3) * 34 + li + (t % 3)) * 8;

    fx16 acc[2];
#pragma unroll
    for (int i = 0; i < 2; ++i)
#pragma unroll
        for (int r = 0; r < 16; ++r) acc[i][r] = 0.f;

    const f16* wb = Wcsw2;
#pragma clang loop unroll(disable)
    for (int rep = 0; rep < REP; ++rep) {
        // opaque pointer laundering: defeats LICM hoisting loads out of reps
        unsigned lo = (unsigned)(unsigned long long)wb;
        unsigned hi = (unsigned)((unsigned long long)wb >> 32);
        asm volatile("" : "+v"(lo), "+v"(hi));
        wb = (const f16*)(((unsigned long long)hi << 32) | lo);

        h8_t abuf[8][2];
#pragma unroll
        for (int pk = 0; pk < 8; ++pk)
#pragma unroll
            for (int i = 0; i < 2; ++i)
                abuf[pk][i] = *(const h8_t*)(wb +
                    (((size_t)pk * 16 + (w * 2 + i)) * 64 + lane) * 8);

#pragma unroll
        for (int ks = 0; ks < 45; ++ks) {
            const int o0 = 2 * ks, o1 = 2 * ks + 1;
            const int a0 = (o0 % 10) * 816 + pxh[o0 / 10];
            const int a1 = (o1 % 10) * 816 + pxh[o1 / 10];
            const h8_t bf = *(const h8_t*)(msT + (q2 ? a1 : a0));
            h8_t av[2];
#pragma unroll
            for (int i = 0; i < 2; ++i) av[i] = abuf[ks & 7][i];
            if (ks + 8 < 45) {
#pragma unroll
                for (int i = 0; i < 2; ++i)
                    abuf[ks & 7][i] = *(const h8_t*)(wb +
                        (((size_t)(ks + 8) * 16 + (w * 2 + i)) * 64 + lane) * 8);
            }
#pragma unroll
            for (int i = 0; i < 2; ++i)
                acc[i] = __builtin_amdgcn_mfma_f32_32x32x16_f16(
                    av[i], bf, acc[i], 0, 0, 0);
        }
    }

    const float r = acc[0][0] + acc[1][1];
    if ((int)blockIdx.x < 0) sink[0] = r;   // never true; keeps loads live
}

// ---------------------------------------------------------------------------
extern "C" void kernel_launch(void* const* d_in, const int* in_sizes, int n_in,
                              void* d_out, int out_size, void* d_ws, size_t ws_size,
                              hipStream_t stream)
{
    const float* z  = (const float*)d_in[0];
    const float* W1 = (const float*)d_in[1];   // 512 x 720
    const float* b1 = (const float*)d_in[2];
    const float* W2 = (const float*)d_in[3];   // 512 x 512
    const float* b2 = (const float*)d_in[4];
    const float* W3 = (const float*)d_in[5];   // 80 x 512
    const float* b3 = (const float*)d_in[6];

    char* ws = (char*)d_ws;
    float* U0    = (float*)ws;  ws += (size_t)80 * NPIX * 4;
    float* U1    = (float*)ws;  ws += (size_t)80 * NPIX * 4;
    float* A0    = (float*)ws;  ws += (size_t)NPIX * 4;
    float* A1    = (float*)ws;  ws += (size_t)NPIX * 4;
    float* bc    = (float*)ws;  ws += 512 * 4;
    float* Wc    = (float*)ws;  ws += (size_t)512 * 720 * 4;
    float* W2T   = (float*)ws;  ws += (size_t)512 * 512 * 4;
    f16*   Wcsw2 = (f16*)ws;   ws += (size_t)45 * 16 * 64 * 8 * 2;
    f16*   W3sw2 = (f16*)ws;   ws += (size_t)32 * 3 * 64 * 8 * 2;

    hipMemsetAsync(U0, 0, (size_t)80 * NPIX * 4, stream);
    hipMemsetAsync(A0, 0, (size_t)NPIX * 4, stream);
    seed2<<<3, 256, 0, stream>>>(z, U0, A0);
    tr512<<<256, 256, 0, stream>>>(W2, W2T);
    wc32<<<dim3(23, 16), 256, 0, stream>>>(W2T, W1, Wc);
    bc_k<<<2, 256, 0, stream>>>(W2, b1, b2, bc);
    swz_wc2<<<180, 256, 0, stream>>>(Wc, Wcsw2);
    swz_w32<<<24, 256, 0, stream>>>(W3, W3sw2);

    float* Uc = U0;  float* Un = U1;
    float* Ac = A0;  float* An = A1;
    for (int s = 0; s < 64; ++s) {
        kS<<<256, 512, 0, stream>>>(Wcsw2, bc, W3sw2, b3, Uc, Ac, Un, An);
        float* t = Uc; Uc = Un; Un = t;
        float* a = Ac; Ac = An; An = a;
    }
    kF<<<256, 128, 0, stream>>>(Uc, Ac, (float*)d_out);

    // ---- probes (measure-only; outputs already final) --------------------
    kW<64><<<256, 512, 0, stream>>>(Wcsw2, W2T);     // mono: top-1 rocprof row
    for (int s = 0; s < 64; ++s)
        kW<1><<<256, 512, 0, stream>>>(Wcsw2, W2T);  // with-boundary chain
}

// Round 10
// 1372.063 us; speedup vs baseline: 3.6339x; 1.6928x over previous
//
#include <hip/hip_runtime.h>

// CAGenerator: 64-step neural CA — TWO dispatches/step, LDS-resident weights.
// R24: probe-driven (R23): kS's binder = phase-1 weight stream from L2 at
//   ~63 GB/s/CU (11.35us of 17.6 isolated by kW<64>); dispatch boundary is
//   cheap (kW<1> = 7.3us incl. full stream). Fix = R18's slab split with the
//   staging done RIGHT: whole 90KB slab -> LDS in one async fill (12x
//   global_load_lds issues, ONE vmcnt(0)+barrier, overlapped with build),
//   then a fully-unrolled pure-LDS 45-iter MFMA loop (no global traffic,
//   no barriers) — kills R18's 12-chunk barrier serialization.
//  kBH: 256 blocks = 8 H-slabs x 32 row-groups (slab = blk&7 -> XCD-local).
//       64 H-ch x 8 rows/block; H -> global octets.
//  kU:  256 blocks x 512 thr (1 row): fp32 S row rebuild (bitwise-same
//       mask), phase2 6-wave K-split (mt x kh) + LDS combine; writes
//       U fp32 ch-major, Um f16 px-major, A plane.
// kF: dout = U63 ch0 * live63.
// Folded: Wc = W2@W1 (512x720), bc = W2@b1+b2. mask=uniform()<1.0 -> no RNG.

#define NPIX 8192
#define T_ALIVE 0.01f

typedef _Float16 f16;
typedef __attribute__((ext_vector_type(8)))  _Float16 h8_t;
typedef __attribute__((ext_vector_type(4)))  _Float16 h4_t;
typedef __attribute__((ext_vector_type(16))) float    fx16;

__device__ __forceinline__ void gld16(const f16* g, f16* l)
{
    __builtin_amdgcn_global_load_lds(
        (const __attribute__((address_space(1))) unsigned int*)(const void*)g,
        (__attribute__((address_space(3))) unsigned int*)(void*)l, 16, 0, 0);
}

// ---------------------------------------------------------------------------
// Prep
// ---------------------------------------------------------------------------
__global__ __launch_bounds__(256) void tr512(
    const float* __restrict__ W2, float* __restrict__ W2T)
{
    __shared__ float t[32][33];
    const int bx = blockIdx.x & 15, by = blockIdx.x >> 4;
    const int x = threadIdx.x & 31, y8 = threadIdx.x >> 5;
#pragma unroll
    for (int r = 0; r < 32; r += 8)
        t[r + y8][x] = W2[(size_t)(by * 32 + r + y8) * 512 + bx * 32 + x];
    __syncthreads();
#pragma unroll
    for (int r = 0; r < 32; r += 8)
        W2T[(size_t)(bx * 32 + r + y8) * 512 + by * 32 + x] = t[x][r + y8];
}

__global__ __launch_bounds__(256) void wc32(
    const float* __restrict__ W2T, const float* __restrict__ W1,
    float* __restrict__ Wc)
{
    __shared__ float As[16][32];
    __shared__ float Bs[16][32];
    const int tid = threadIdx.x;
    const int ty = tid >> 3, tx = tid & 7;
    const int m0 = blockIdx.y * 32, n0 = blockIdx.x * 32;
    float acc[4] = {0.f, 0.f, 0.f, 0.f};

    for (int k0 = 0; k0 < 512; k0 += 16) {
#pragma unroll
        for (int t = 0; t < 2; ++t) {
            const int idx = tid + t * 256;
            const int r = idx >> 5, c = idx & 31;
            As[r][c] = W2T[(size_t)(k0 + r) * 512 + m0 + c];
            const int n = n0 + c;
            Bs[r][c] = (n < 720) ? W1[(size_t)(k0 + r) * 720 + n] : 0.f;
        }
        __syncthreads();
#pragma unroll
        for (int kk = 0; kk < 16; ++kk) {
            const float a = As[kk][ty];
#pragma unroll
            for (int j = 0; j < 4; ++j)
                acc[j] = fmaf(a, Bs[kk][tx * 4 + j], acc[j]);
        }
        __syncthreads();
    }
    const int m = m0 + ty;
#pragma unroll
    for (int j = 0; j < 4; ++j) {
        const int n = n0 + tx * 4 + j;
        if (n < 720) Wc[(size_t)m * 720 + n] = acc[j];
    }
}

__global__ __launch_bounds__(256) void bc_k(
    const float* __restrict__ W2, const float* __restrict__ b1,
    const float* __restrict__ b2, float* __restrict__ bc)
{
    const int m = blockIdx.x * 256 + threadIdx.x;
    if (m >= 512) return;
    float a = b2[m];
    for (int h = 0; h < 512; ++h) a += W2[m * 512 + h] * b1[h];
    bc[m] = a;
}

// Slab-major LINEAR weight frags (matches LDS fill order exactly):
// slot = ((h*45 + ck)*2 + i)*64 + lane ; 16B per slot. K permuted
// (kp = tap*80+ci). Slab h = m-tiles 2h, 2h+1 (H-channels h*64..h*64+63).
__global__ __launch_bounds__(256) void swz_wh(
    const float* __restrict__ Wc, f16* __restrict__ Wh)
{
    const int idx = blockIdx.x * 256 + threadIdx.x;
    if (idx >= 46080) return;
    const int lane = idx & 63;
    int t = idx >> 6;
    const int i = t & 1; t >>= 1;
    const int ck = t % 45, h = t / 45;
    const int m = (h * 2 + i) * 32 + (lane & 31);
    const int k0 = ck * 16 + (lane >> 5) * 8;
    h8_t v;
#pragma unroll
    for (int j = 0; j < 8; ++j) {
        const int kp = k0 + j;
        const int tap = kp / 80, ci = kp - tap * 80;
        v[j] = (f16)Wc[(size_t)m * 720 + ci * 9 + tap];
    }
    *(h8_t*)(Wh + (size_t)idx * 8) = v;
}

// 32x32x16 A-frags for W3 (80x512 padded to 96 rows).
__global__ __launch_bounds__(256) void swz_w32(
    const float* __restrict__ W3, f16* __restrict__ W3sw2)
{
    const int idx = blockIdx.x * 256 + threadIdx.x;
    if (idx >= 32 * 3 * 64) return;
    const int lane = idx & 63;
    const int t = idx >> 6;
    const int mt = t % 3, ks2 = t / 3;
    const int m = mt * 32 + (lane & 31);
    const int k0 = ks2 * 16 + (lane >> 5) * 8;
    h8_t v;
#pragma unroll
    for (int j = 0; j < 8; ++j)
        v[j] = (f16)((m < 80) ? W3[(size_t)m * 512 + k0 + j] : 0.f);
    *(h8_t*)(W3sw2 + (size_t)idx * 8) = v;
}

// Seed: U_{-1} := S_0 (fp32 ch-major), Um_{-1} := f16 px-major, A_{-1} := ch0.
__global__ __launch_bounds__(256) void seed3(
    const float* __restrict__ z, float* __restrict__ U0,
    f16* __restrict__ Um0, float* __restrict__ A0)
{
    const int idx = blockIdx.x * 256 + threadIdx.x;
    if (idx >= 640) return;
    const int b = idx / 80, c = idx - b * 80;
    const int n = b * 1024 + 16 * 32 + 16;
    const float v = (c == 0) ? 1.f : z[b * 100 + (c - 1)];
    U0[(size_t)c * NPIX + n] = v;
    Um0[(size_t)n * 80 + c] = (f16)v;
    if (c == 0) A0[n] = 1.f;
}

// ---------------------------------------------------------------------------
// kBH: H-slab x row-group. grid 256 x 512 thr. blk: h = blk&7 (slab/XCD),
//   g = blk>>3; b = g>>2, y0 = (g&3)*8; rows y0..y0+7, wave w = row y0+w.
//   Slab weights -> LDS once (async, overlapped with build); main loop is
//   pure LDS: 45 x {2 ds_read(A) + 1 ds_read(B) + 2 MFMA}, no barriers.
// ---------------------------------------------------------------------------
__global__ __launch_bounds__(512) void kBH(
    const f16* __restrict__ Wh, const float* __restrict__ bc,
    const f16* __restrict__ Um, const float* __restrict__ Nw,  // U_prev ch0
    const float* __restrict__ Ap, f16* __restrict__ Hout)
{
    __shared__ f16   Wslab[46080];   // 45 ck x 2 tiles x 512 halfs = 92160 B
    __shared__ f16   msT[27200];     // 10 cc x 10 rows x 34 px x 8 halfs
    __shared__ float bcL[64];
    __shared__ float N12[384];
    __shared__ float A12[384];
    __shared__ float live10[320];

    const int tid = threadIdx.x;
    const int lane = tid & 63, w = tid >> 6;
    const int li = lane & 31, q2 = lane >> 5;
    const int blk = blockIdx.x;
    const int h = blk & 7, g = blk >> 3;
    const int b = g >> 2, y0 = (g & 3) * 8;
    const int gb = b * 1024;
    const f16* Whb = Wh + (size_t)h * 46080;   // 5760 slots x 8 halfs

    // single-shot async slab fill: 5760 16B slots, 12 rounds x 512 thr
#pragma unroll
    for (int j = 0; j < 12; ++j) {
        const int slot = j * 512 + tid;
        if (slot < 5760)     // j=11: tid<128 -> waves 0,1 whole (uniform)
            gld16(Whb + (size_t)slot * 8, Wslab + (size_t)slot * 8);
    }

    if (tid < 64) bcL[tid] = bc[h * 64 + tid];

    // ---------------- build: live mask + masked f16 state -----------------
    if (tid < 384) {
        const int r = tid >> 5, x = tid & 31, yy = y0 - 2 + r;
        const bool ok = ((unsigned)yy < 32u);
        N12[tid] = ok ? Nw[gb + yy * 32 + x] : -1e30f;
        A12[tid] = ok ? Ap[gb + yy * 32 + x] : -1e30f;
    }
    __syncthreads();

    if (tid < 320) {   // live rows y0-1..y0+8
        const int r = tid >> 5, x = tid & 31;
        float mN = -1e30f, mA = -1e30f;
#pragma unroll
        for (int rr = 0; rr < 3; ++rr)
#pragma unroll
            for (int dx = -1; dx <= 1; ++dx) {
                const int xx = x + dx;
                if ((unsigned)xx < 32u) {
                    mN = fmaxf(mN, N12[(r + rr) * 32 + xx]);
                    mA = fmaxf(mA, A12[(r + rr) * 32 + xx]);
                }
            }
        live10[tid] = (mN > T_ALIVE && mA > T_ALIVE) ? 1.f : 0.f;
    }
    __syncthreads();

    {   // msT = Um * live, 10 rows x 10 cc x 32 px; plus halo cols
        h8_t zz;
#pragma unroll
        for (int j = 0; j < 8; ++j) zz[j] = (f16)0.f;
        for (int q = tid; q < 3200; q += 512) {
            const int r = q / 320, rem = q - r * 320;
            const int cc = rem >> 5, x = rem & 31;
            const int yy = y0 - 1 + r;
            h8_t v = zz;
            if (((unsigned)yy < 32u) && live10[r * 32 + x] != 0.f)
                v = *(const h8_t*)(Um + (size_t)(gb + yy * 32 + x) * 80 + cc * 8);
            *(h8_t*)(msT + (size_t)((cc * 10 + r) * 34 + x + 1) * 8) = v;
        }
        if (tid < 200) {   // halo columns xi = 0, 33
            const int cc = tid / 20, rem = tid % 20;
            const int r = rem >> 1, xi = (rem & 1) * 33;
            *(h8_t*)(msT + (size_t)((cc * 10 + r) * 34 + xi) * 8) = zz;
        }
    }
    asm volatile("s_waitcnt vmcnt(0)" ::: "memory");   // slab arrival
    __syncthreads();

    // ---------------- main loop: pure-LDS, fully unrolled -----------------
    int pxh[9];
#pragma unroll
    for (int t = 0; t < 9; ++t)
        pxh[t] = ((t / 3) * 34 + li + (t % 3)) * 8;

    fx16 acc0, acc1;
#pragma unroll
    for (int r = 0; r < 16; ++r) { acc0[r] = 0.f; acc1[r] = 0.f; }

    const int wbase = w * 272;   // w*34*8 halfs
#pragma unroll
    for (int ks = 0; ks < 45; ++ks) {
        const int o = 2 * ks + q2;
        const int cc = o % 10, t = o / 10;
        const h8_t bf = *(const h8_t*)(msT + cc * 2720 + wbase + pxh[t]);
        const h8_t a0 = *(const h8_t*)(Wslab + ((size_t)ks * 2    ) * 512 + lane * 8);
        const h8_t a1 = *(const h8_t*)(Wslab + ((size_t)ks * 2 + 1) * 512 + lane * 8);
        acc0 = __builtin_amdgcn_mfma_f32_32x32x16_f16(a0, bf, acc0, 0, 0, 0);
        acc1 = __builtin_amdgcn_mfma_f32_32x32x16_f16(a1, bf, acc1, 0, 0, 0);
    }

    // ---------------- epilogue: relu(acc + bc) -> H global ----------------
    const int R = b * 32 + y0 + w;
#pragma unroll
    for (int i = 0; i < 2; ++i) {
#pragma unroll
        for (int aa = 0; aa < 4; ++aa) {
            const int chl = i * 32 + 8 * aa + 4 * q2;
            const int co = h * 8 + i * 4 + aa;
            h4_t v4;
            const fx16& ac = i ? acc1 : acc0;
#pragma unroll
            for (int rb = 0; rb < 4; ++rb)
                v4[rb] = (f16)fmaxf(ac[aa * 4 + rb] + bcL[chl + rb], 0.f);
            *(h4_t*)(Hout + ((size_t)(R * 64 + co) * 32 + li) * 8 + 4 * q2) = v4;
        }
    }
}

// ---------------------------------------------------------------------------
// kU: one row per block. grid 256 x 512 thr. blk = R = b*32+y.
//   fp32 S row rebuild (same live math), phase2 6-wave K-split (mt x kh)
//   with LDS combine; writes U fp32 + Um f16 px-major + A plane.
// ---------------------------------------------------------------------------
__global__ __launch_bounds__(512) void kU(
    const f16* __restrict__ W3sw2, const float* __restrict__ b3,
    const f16* __restrict__ Hin, const float* __restrict__ Uin,
    const float* __restrict__ Ain,
    float* __restrict__ Uout, f16* __restrict__ Umout,
    float* __restrict__ Aout)
{
    __shared__ float SrowL[2560];
    __shared__ float UrowL[2560];
    __shared__ float Pacc[3072];    // 3 mt x 16 r x 64 lanes
    __shared__ float N3[96];
    __shared__ float A3[96];
    __shared__ float liveR[32];
    __shared__ float b3L[80];

    const int tid = threadIdx.x;
    const int lane = tid & 63, w = tid >> 6;
    const int li = lane & 31, q2 = lane >> 5;
    const int blk = blockIdx.x;
    const int b = blk >> 5, y = blk & 31;
    const int gb = b * 1024;
    const int base = gb + y * 32;
    const f16* Hrow = Hin + (size_t)blk * 16384;

    // prologue: W3 + H rings for waves 0..5 (mt = w%3, kh = w/3)
    const int mt = w % 3;
    const int kb = (w >= 3 && w < 6) ? 16 : 0;
    h8_t ar[8], hr[8];
    if (w < 6) {
#pragma unroll
        for (int pk = 0; pk < 8; ++pk) {
            ar[pk] = *(const h8_t*)(W3sw2 +
                (((size_t)(kb + pk) * 3 + mt) * 64 + lane) * 8);
            hr[pk] = *(const h8_t*)(Hrow +
                ((size_t)((kb + pk) * 2 + q2) * 32 + li) * 8);
        }
    }
    if (tid < 80) b3L[tid] = b3[tid];
    if (tid < 96) {
        const int r = tid >> 5, x = tid & 31, yy = y - 1 + r;
        const bool ok = ((unsigned)yy < 32u);
        N3[tid] = ok ? Uin[gb + yy * 32 + x] : -1e30f;
        A3[tid] = ok ? Ain[gb + yy * 32 + x] : -1e30f;
    }
    __syncthreads();

    if (tid < 32) {
        float mN = -1e30f, mA = -1e30f;
#pragma unroll
        for (int rr = 0; rr < 3; ++rr)
#pragma unroll
            for (int dx = -1; dx <= 1; ++dx) {
                const int xx = tid + dx;
                if ((unsigned)xx < 32u) {
                    mN = fmaxf(mN, N3[rr * 32 + xx]);
                    mA = fmaxf(mA, A3[rr * 32 + xx]);
                }
            }
        liveR[tid] = (mN > T_ALIVE && mA > T_ALIVE) ? 1.f : 0.f;
    }
    __syncthreads();

    // S row (fp32) + A_out
#pragma unroll
    for (int it = 0; it < 5; ++it) {
        const int q = tid + it * 512;
        const int ch = q >> 5, x = q & 31;
        const float v = Uin[(size_t)ch * NPIX + base + x] * liveR[x];
        SrowL[q] = v;
        if (ch == 0) Aout[base + x] = v;
    }
    __syncthreads();

    // phase 2: upd = W3*H, K split (kh0: ks2 0..15, kh1: 16..31)
    fx16 acc3;
#pragma unroll
    for (int r = 0; r < 16; ++r) acc3[r] = 0.f;
    if (w < 6) {
#pragma unroll
        for (int i = 0; i < 16; ++i) {
            const h8_t a  = ar[i & 7];
            const h8_t bf = hr[i & 7];
            if (i + 8 < 16) {
                ar[i & 7] = *(const h8_t*)(W3sw2 +
                    (((size_t)(kb + i + 8) * 3 + mt) * 64 + lane) * 8);
                hr[i & 7] = *(const h8_t*)(Hrow +
                    ((size_t)((kb + i + 8) * 2 + q2) * 32 + li) * 8);
            }
            acc3 = __builtin_amdgcn_mfma_f32_32x32x16_f16(a, bf, acc3, 0, 0, 0);
        }
    }
    if (w >= 3 && w < 6) {
#pragma unroll
        for (int r = 0; r < 16; ++r)
            Pacc[((size_t)mt * 16 + r) * 64 + lane] = acc3[r];
    }
    __syncthreads();
    if (w < 3) {
#pragma unroll
        for (int r = 0; r < 16; ++r)
            acc3[r] += Pacc[((size_t)w * 16 + r) * 64 + lane];
#pragma unroll
        for (int aa = 0; aa < 4; ++aa)
#pragma unroll
            for (int rb = 0; rb < 4; ++rb) {
                const int ch = w * 32 + rb + 8 * aa + 4 * q2;
                if (ch < 80) {
                    const float uv = SrowL[ch * 32 + li]
                                   + acc3[aa * 4 + rb] + b3L[ch];
                    Uout[(size_t)ch * NPIX + base + li] = uv;
                    UrowL[ch * 32 + li] = uv;
                }
            }
    }
    __syncthreads();

    // Um (f16 px-major) from UrowL
    for (int q = tid; q < 640; q += 512) {
        const int cq = q >> 5, x = q & 31;
        h4_t v4;
#pragma unroll
        for (int rb = 0; rb < 4; ++rb)
            v4[rb] = (f16)UrowL[(cq * 4 + rb) * 32 + x];
        *(h4_t*)(Umout + (size_t)(base + x) * 80 + cq * 4) = v4;
    }
}

// ---------------------------------------------------------------------------
// kF: dout = U63 ch0 * live63. grid 256 x 128 thr.
// ---------------------------------------------------------------------------
__global__ __launch_bounds__(128) void kF(
    const float* __restrict__ Uf, const float* __restrict__ Af,
    float* __restrict__ dout)
{
    __shared__ float N3[96];
    __shared__ float A3[96];
    const int tid = threadIdx.x;
    const int blk = blockIdx.x;
    const int b = blk >> 5, y = blk & 31;
    const int gb = b * 1024;

    if (tid < 96) {
        const int r = tid >> 5, x = tid & 31, yy = y - 1 + r;
        const bool ok = ((unsigned)yy < 32u);
        N3[tid] = ok ? Uf[gb + yy * 32 + x] : -1e30f;
        A3[tid] = ok ? Af[gb + yy * 32 + x] : -1e30f;
    }
    __syncthreads();

    if (tid < 32) {
        float mN = -1e30f, mA = -1e30f;
#pragma unroll
        for (int rr = 0; rr < 3; ++rr)
#pragma unroll
            for (int dx = -1; dx <= 1; ++dx) {
                const int xx = tid + dx;
                if ((unsigned)xx < 32u) {
                    mN = fmaxf(mN, N3[rr * 32 + xx]);
                    mA = fmaxf(mA, A3[rr * 32 + xx]);
                }
            }
        const float lv = (mN > T_ALIVE && mA > T_ALIVE) ? 1.f : 0.f;
        dout[gb + y * 32 + tid] = Uf[gb + y * 32 + tid] * lv;
    }
}

// ---------------------------------------------------------------------------
extern "C" void kernel_launch(void* const* d_in, const int* in_sizes, int n_in,
                              void* d_out, int out_size, void* d_ws, size_t ws_size,
                              hipStream_t stream)
{
    const float* z  = (const float*)d_in[0];
    const float* W1 = (const float*)d_in[1];   // 512 x 720
    const float* b1 = (const float*)d_in[2];
    const float* W2 = (const float*)d_in[3];   // 512 x 512
    const float* b2 = (const float*)d_in[4];
    const float* W3 = (const float*)d_in[5];   // 80 x 512
    const float* b3 = (const float*)d_in[6];

    char* ws = (char*)d_ws;
    float* U0    = (float*)ws;  ws += (size_t)80 * NPIX * 4;
    float* U1    = (float*)ws;  ws += (size_t)80 * NPIX * 4;
    f16*   Um0   = (f16*)ws;   ws += (size_t)NPIX * 80 * 2;
    f16*   Um1   = (f16*)ws;   ws += (size_t)NPIX * 80 * 2;
    float* A0    = (float*)ws;  ws += (size_t)NPIX * 4;
    float* A1    = (float*)ws;  ws += (size_t)NPIX * 4;
    f16*   Hbuf  = (f16*)ws;   ws += (size_t)256 * 64 * 32 * 8 * 2;
    float* bc    = (float*)ws;  ws += 512 * 4;
    float* Wc    = (float*)ws;  ws += (size_t)512 * 720 * 4;
    float* W2T   = (float*)ws;  ws += (size_t)512 * 512 * 4;
    f16*   Wh    = (f16*)ws;   ws += (size_t)46080 * 8 * 2;
    f16*   W3sw2 = (f16*)ws;   ws += (size_t)32 * 3 * 64 * 8 * 2;

    hipMemsetAsync(U0, 0, (size_t)80 * NPIX * 4, stream);
    hipMemsetAsync(Um0, 0, (size_t)NPIX * 80 * 2, stream);
    hipMemsetAsync(A0, 0, (size_t)NPIX * 4, stream);
    seed3<<<3, 256, 0, stream>>>(z, U0, Um0, A0);
    tr512<<<256, 256, 0, stream>>>(W2, W2T);
    wc32<<<dim3(23, 16), 256, 0, stream>>>(W2T, W1, Wc);
    bc_k<<<2, 256, 0, stream>>>(W2, b1, b2, bc);
    swz_wh<<<180, 256, 0, stream>>>(Wc, Wh);
    swz_w32<<<24, 256, 0, stream>>>(W3, W3sw2);

    float* Uc = U0;  float* Un = U1;
    f16*   Mc = Um0; f16*   Mn = Um1;
    float* Ac = A0;  float* An = A1;
    for (int s = 0; s < 64; ++s) {
        kBH<<<256, 512, 0, stream>>>(Wh, bc, Mc, Uc, Ac, Hbuf);
        kU<<<256, 512, 0, stream>>>(W3sw2, b3, Hbuf, Uc, Ac, Un, Mn, An);
        float* t = Uc; Uc = Un; Un = t;
        f16*   m = Mc; Mc = Mn; Mn = m;
        float* a = Ac; Ac = An; An = a;
    }
    kF<<<256, 128, 0, stream>>>(Uc, Ac, (float*)d_out);
}